// Round 1
// baseline (340.935 us; speedup 1.0000x reference)
//
#include <hip/hip_runtime.h>
#include <math.h>

// ---------------------------------------------------------------------------
// GeoFeatureExtractor: B=256, T=512, N=51 landmarks x 3 (fp32), 114 features.
// One thread per (b,t). Temporal features (_cdiff) emulated exactly including
// edge-replication boundaries. Output layout: out[(b*T+t)*114 + f].
// ---------------------------------------------------------------------------

#define NF 114
#define NLM 51

struct V3 { float x, y, z; };

__device__ __forceinline__ V3 operator-(V3 a, V3 b) { return {a.x - b.x, a.y - b.y, a.z - b.z}; }
__device__ __forceinline__ V3 operator+(V3 a, V3 b) { return {a.x + b.x, a.y + b.y, a.z + b.z}; }
__device__ __forceinline__ V3 operator*(V3 a, float s) { return {a.x * s, a.y * s, a.z * s}; }
__device__ __forceinline__ float dot3(V3 a, V3 b) { return a.x * b.x + a.y * b.y + a.z * b.z; }
__device__ __forceinline__ V3 cross3(V3 a, V3 b) {
    return {a.y * b.z - a.z * b.y, a.z * b.x - a.x * b.z, a.x * b.y - a.y * b.x};
}
__device__ __forceinline__ float norm3(V3 a) { return sqrtf(dot3(a, a)); }
__device__ __forceinline__ float dist3(V3 a, V3 b) { V3 d = a - b; return sqrtf(dot3(d, d) + 1e-6f); }
__device__ __forceinline__ float acosc(float c) {
    c = fminf(fmaxf(c, -1.0f + 1e-6f), 1.0f - 1e-6f);
    return acosf(c);
}

__constant__ int c_TRI[15][3] = {
    {0, 1, 2},   {1, 2, 3},   {2, 3, 4},
    {0, 5, 6},   {5, 6, 7},   {6, 7, 8},
    {0, 9, 10},  {9, 10, 11}, {10, 11, 12},
    {0, 13, 14}, {13, 14, 15},{14, 15, 16},
    {0, 17, 18}, {17, 18, 19},{18, 19, 20}};

__global__ __launch_bounds__(256) void geo_kernel(
    const float* __restrict__ xyz,
    const float* __restrict__ fmask,
    const float* __restrict__ bmask,
    float* __restrict__ out,
    int BT, int T)
{
    int idx = blockIdx.x * blockDim.x + threadIdx.x;
    if (idx >= BT) return;
    int b = idx / T;
    int t = idx - b * T;
    int bT0 = b * T;

    // load landmark lm at timestep tt (absolute within this batch row)
    auto ldp = [&](int tt, int lm) -> V3 {
        const float* p = xyz + ((size_t)(bT0 + tt) * NLM + (size_t)lm) * 3;
        return V3{p[0], p[1], p[2]};
    };
    auto P = [&](int lm) -> V3 { return ldp(t, lm); };

    // central diff with edge replication, exact _cdiff semantics
    auto velAt = [&](int lm, int tt) -> V3 {
        int ta, tb;
        if (tt == 0)           { ta = 0;     tb = 2;     }
        else if (tt == T - 1)  { ta = T - 3; tb = T - 1; }
        else                   { ta = tt - 1; tb = tt + 1; }
        return (ldp(tb, lm) - ldp(ta, lm)) * 0.5f;
    };
    auto accAt = [&](int lm, int tt) -> V3 {
        int ta, tb;
        if (tt == 0)           { ta = 0;     tb = 2;     }
        else if (tt == T - 1)  { ta = T - 3; tb = T - 1; }
        else                   { ta = tt - 1; tb = tt + 1; }
        return (velAt(lm, tb) - velAt(lm, ta)) * 0.5f;
    };

    float fg = fmask[idx];
    float bg = bmask[idx];
    float* o = out + (size_t)idx * NF;

    // ---------------- Block A: tips + curls + cross + d_ti (f 0..23) -------
    for (int h = 0; h < 2; ++h) {
        int base = h * 21;
        V3 t_tip = P(base + 4),  i_tip = P(base + 8),  m_tip = P(base + 12);
        V3 r_tip = P(base + 16), p_tip = P(base + 20);
        float* oa = o + h * 12;
        oa[0] = dist3(t_tip, i_tip);
        oa[1] = dist3(i_tip, m_tip);
        oa[2] = dist3(m_tip, r_tip);
        oa[3] = dist3(r_tip, p_tip);
        oa[4] = dist3(t_tip, p_tip);
        V3 tm = P(base + 2),  tip_j = P(base + 3);
        oa[5] = dist3(tm, t_tip) / (dist3(tm, tip_j) + 1e-4f);
        V3 im = P(base + 5),  ipj = P(base + 6);
        oa[6] = dist3(im, i_tip) / (dist3(im, ipj) + 1e-4f);
        V3 mm = P(base + 9),  mpj = P(base + 10);
        oa[7] = dist3(mm, m_tip) / (dist3(mm, mpj) + 1e-4f);
        V3 rm = P(base + 13), rpj = P(base + 14);
        oa[8] = dist3(rm, r_tip) / (dist3(rm, rpj) + 1e-4f);
        V3 pm = P(base + 17), ppj = P(base + 18);
        oa[9] = dist3(pm, p_tip) / (dist3(pm, ppj) + 1e-4f);
        oa[10] = i_tip.x - m_tip.x;
        oa[11] = dist3(t_tip, im);
    }

    // ---------------- Block B: face distances * fg (f 24..33) --------------
    V3 p0 = P(0), p21 = P(21);
    V3 nose = P(42), chin = P(43), fore = P(44);
    V3 itip0 = P(8), itip1 = P(29);
    o[24] = dist3(p0, nose) * fg;
    o[25] = dist3(p0, chin) * fg;
    o[26] = dist3(p0, fore) * fg;
    o[27] = dist3(p21, nose) * fg;
    o[28] = dist3(p21, chin) * fg;
    o[29] = dist3(p21, fore) * fg;
    o[30] = dist3(itip0, nose) * fg;
    o[31] = dist3(itip0, fore) * fg;
    o[32] = dist3(itip1, nose) * fg;
    o[33] = dist3(itip1, fore) * fg;

    // ---------------- Block C: joint angles (f 34..63) ---------------------
    for (int h = 0; h < 2; ++h) {
        int base = h * 21;
        for (int i = 0; i < 15; ++i) {
            V3 pj = P(base + c_TRI[i][1]);
            V3 v1 = P(base + c_TRI[i][0]) - pj;
            V3 v2 = P(base + c_TRI[i][2]) - pj;
            o[34 + h * 15 + i] = acosc(dot3(v1, v2) / (norm3(v1) * norm3(v2) + 1e-6f));
        }
    }

    // ---------------- Block D: palm normals (f 64..69) ---------------------
    V3 nrm[2];
    for (int h = 0; h < 2; ++h) {
        int base = h * 21;
        V3 w = (h == 0) ? p0 : p21;
        V3 n = cross3(P(base + 5) - w, P(base + 17) - w);
        float inv = 1.0f / (norm3(n) + 1e-6f);
        n = n * inv;
        nrm[h] = n;
        o[64 + 3 * h + 0] = n.x;
        o[64 + 3 * h + 1] = n.y;
        o[64 + 3 * h + 2] = n.z;
    }

    // ---------------- Block E: spread angles (f 70..75) --------------------
    for (int h = 0; h < 2; ++h) {
        int base = h * 21;
        V3 w = (h == 0) ? p0 : p21;
        V3 v5  = P(base + 5)  - w;
        V3 v9  = P(base + 9)  - w;
        V3 v13 = P(base + 13) - w;
        V3 v17 = P(base + 17) - w;
        o[70 + 3 * h + 0] = acosc(dot3(v5,  v9)  / (norm3(v5)  * norm3(v9)  + 1e-6f));
        o[70 + 3 * h + 1] = acosc(dot3(v9,  v13) / (norm3(v9)  * norm3(v13) + 1e-6f));
        o[70 + 3 * h + 2] = acosc(dot3(v13, v17) / (norm3(v13) * norm3(v17) + 1e-6f));
    }

    // ---------------- Block F: n . up, n . fwd (f 76..79) ------------------
    for (int h = 0; h < 2; ++h) {
        o[76 + 2 * h + 0] = nrm[h].y;
        o[76 + 2 * h + 1] = nrm[h].z;
    }

    // ---------------- Block G: velocity direction (f 80..85) ---------------
    V3 velW[2];
    for (int h = 0; h < 2; ++h) {
        V3 v = velAt(h * 21, t);
        velW[h] = v;
        float inv = 1.0f / fmaxf(norm3(v), 1e-6f);   // jnp.maximum semantics
        o[80 + 3 * h + 0] = v.x * inv;
        o[80 + 3 * h + 1] = v.y * inv;
        o[80 + 3 * h + 2] = v.z * inv;
    }

    // ---------------- Block H: velocity-turn angle (f 86..87) --------------
    for (int h = 0; h < 2; ++h) {
        float val = 0.0f;
        if (t < T - 1) {
            V3 v0 = velW[h];
            V3 v1 = velAt(h * 21, t + 1);
            V3 a = v0 * (1.0f / (norm3(v0) + 1e-6f));
            V3 c = v1 * (1.0f / (norm3(v1) + 1e-6f));
            val = acosc(dot3(a, c));
        }
        o[86 + h] = val;
    }

    // ---------------- Block I/J: inter-hand (f 88..90) ---------------------
    o[88] = dist3(p0, p21);
    {
        V3 rel = p21 - p0;
        float inv = 1.0f / (norm3(rel) + 1e-6f);
        o[89] = rel.x * inv;
        o[90] = rel.y * inv;
    }

    // ---------------- Block K: d/dt dist-to-nose (f 91..92) ----------------
    for (int h = 0; h < 2; ++h) {
        int lm = h * 21;
        int ta, tb;
        if (t == 0)          { ta = 0;     tb = 2;     }
        else if (t == T - 1) { ta = T - 3; tb = T - 1; }
        else                 { ta = t - 1; tb = t + 1; }
        float da = norm3(ldp(ta, lm) - ldp(ta, 42));
        float db = norm3(ldp(tb, lm) - ldp(tb, 42));
        o[91 + h] = (db - da) * 0.5f;
    }

    // ---------------- Block L: tip x-diffs (f 93..96) ----------------------
    for (int h = 0; h < 2; ++h) {
        int base = h * 21;
        float ix = P(base + 8).x, mx = P(base + 12).x, rx = P(base + 16).x;
        o[93 + 2 * h + 0] = ix - mx;
        o[93 + 2 * h + 1] = mx - rx;
    }

    // ---------------- Block M: hand-velocity alignment (f 97) --------------
    {
        V3 ld = velW[0] * (1.0f / (norm3(velW[0]) + 1e-6f));
        V3 rd = velW[1] * (1.0f / (norm3(velW[1]) + 1e-6f));
        o[97] = dot3(ld, rd);
    }

    // ---------------- Block N: speed (f 98..99) ----------------------------
    o[98] = norm3(velW[0]);
    o[99] = norm3(velW[1]);

    // ---------------- Block O: accel magnitude (f 100..101) ----------------
    o[100] = norm3(accAt(0, t));
    o[101] = norm3(accAt(21, t));

    // ---------------- Block P: proximity sigmoid (f 102) -------------------
    {
        float hd = norm3(p0 - p21);
        o[102] = 1.0f / (1.0f + expf(-5.0f * (0.05f - hd)));
    }

    // ---------------- Block Q: body features * bg (f 103..113) -------------
    {
        V3 lsh = P(45), rsh = P(46);
        V3 shmid = (lsh + rsh) * 0.5f;
        float shw = dist3(lsh, rsh);
        float invw = 1.0f / (shw + 1e-6f);
        o[103] = (p0.y - shmid.y) * invw * bg;
        o[104] = (p0.x - shmid.x) * invw * bg;
        o[105] = dist3(p0, lsh) * bg;
        o[106] = dist3(p0, P(47)) * bg;
        o[107] = (p21.y - shmid.y) * invw * bg;
        o[108] = (p21.x - shmid.x) * invw * bg;
        o[109] = dist3(p21, rsh) * bg;
        o[110] = dist3(p21, P(48)) * bg;
        o[111] = shw * bg;
        V3 mouth = (P(49) + P(50)) * 0.5f;
        o[112] = dist3(p0, mouth) * bg;
        o[113] = dist3(p21, mouth) * bg;
    }
}

extern "C" void kernel_launch(void* const* d_in, const int* in_sizes, int n_in,
                              void* d_out, int out_size, void* d_ws, size_t ws_size,
                              hipStream_t stream) {
    const float* xyz   = (const float*)d_in[0];
    const float* fmask = (const float*)d_in[1];
    const float* bmask = (const float*)d_in[2];
    float* out = (float*)d_out;

    const int BT = in_sizes[1];   // B*T = 131072 (face_mask element count)
    const int T  = 512;           // per reference setup_inputs

    const int threads = 256;
    const int blocks = (BT + threads - 1) / threads;
    geo_kernel<<<blocks, threads, 0, stream>>>(xyz, fmask, bmask, out, BT, T);
}

// Round 2
// 206.524 us; speedup vs baseline: 1.6508x; 1.6508x over previous
//
#include <hip/hip_runtime.h>
#include <math.h>

// ---------------------------------------------------------------------------
// GeoFeatureExtractor: B=256, T=512, N=51 landmarks x 3 (fp32), 114 features.
// Round 2: coalesce everything.
//   K1: transpose xyz [BT][153] -> xyzT [153][BT] in d_ws (LDS 32x33 tiles).
//   K2: one thread per (b,t); all loads stride-1 across lanes via xyzT;
//       features buffered in a register array F[114], burst-stored at end.
// Fallback to the (correct, slow) direct kernel if ws_size is too small.
// ---------------------------------------------------------------------------

#define NF 114
#define NLM 51
#define NC 153   // 51 * 3 coordinates per timestep

struct V3 { float x, y, z; };

__device__ __forceinline__ V3 operator-(V3 a, V3 b) { return {a.x - b.x, a.y - b.y, a.z - b.z}; }
__device__ __forceinline__ V3 operator+(V3 a, V3 b) { return {a.x + b.x, a.y + b.y, a.z + b.z}; }
__device__ __forceinline__ V3 operator*(V3 a, float s) { return {a.x * s, a.y * s, a.z * s}; }
__device__ __forceinline__ float dot3(V3 a, V3 b) { return a.x * b.x + a.y * b.y + a.z * b.z; }
__device__ __forceinline__ V3 cross3(V3 a, V3 b) {
    return {a.y * b.z - a.z * b.y, a.z * b.x - a.x * b.z, a.x * b.y - a.y * b.x};
}
__device__ __forceinline__ float norm3(V3 a) { return sqrtf(dot3(a, a)); }
__device__ __forceinline__ float dist3(V3 a, V3 b) { V3 d = a - b; return sqrtf(dot3(d, d) + 1e-6f); }
__device__ __forceinline__ float acosc(float c) {
    c = fminf(fmaxf(c, -1.0f + 1e-6f), 1.0f - 1e-6f);
    return acosf(c);
}

// ---------------------------------------------------------------------------
// K1: transpose [BT][NC] -> [NC][BT]
// ---------------------------------------------------------------------------
#define TDIM 32
__global__ __launch_bounds__(256) void transpose_kernel(
    const float* __restrict__ in, float* __restrict__ outT, int BT)
{
    __shared__ float tile[TDIM][TDIM + 1];
    int r0 = blockIdx.x * TDIM;   // bt tile
    int c0 = blockIdx.y * TDIM;   // coord tile
    int tx = threadIdx.x;         // 0..31
    int ty = threadIdx.y;         // 0..7

    #pragma unroll
    for (int i = ty; i < TDIM; i += 8) {
        int r = r0 + i, c = c0 + tx;
        if (r < BT && c < NC)
            tile[i][tx] = in[(size_t)r * NC + c];
    }
    __syncthreads();
    #pragma unroll
    for (int i = ty; i < TDIM; i += 8) {
        int c = c0 + i, r = r0 + tx;
        if (r < BT && c < NC)
            outT[(size_t)c * BT + r] = tile[tx][i];
    }
}

// ---------------------------------------------------------------------------
// K2: main compute, transposed input, register-buffered output
// ---------------------------------------------------------------------------
__global__ __launch_bounds__(256) void geo_fast(
    const float* __restrict__ xt,     // [NC][BT]
    const float* __restrict__ fmask,
    const float* __restrict__ bmask,
    float* __restrict__ out,
    int BT, int T)
{
    int idx = blockIdx.x * blockDim.x + threadIdx.x;
    if (idx >= BT) return;
    int b = idx / T;
    int t = idx - b * T;
    int bT0 = b * T;

    auto ld = [&](int c, int tt) -> float {
        return xt[(size_t)c * BT + (size_t)(bT0 + tt)];
    };
    auto Pt = [&](int lm, int tt) -> V3 {
        return V3{ld(3 * lm + 0, tt), ld(3 * lm + 1, tt), ld(3 * lm + 2, tt)};
    };
    auto P = [&](int lm) -> V3 { return Pt(lm, t); };

    auto velAt = [&](int lm, int tt) -> V3 {
        int ta, tb;
        if (tt == 0)           { ta = 0;      tb = 2;     }
        else if (tt == T - 1)  { ta = T - 3;  tb = T - 1; }
        else                   { ta = tt - 1; tb = tt + 1; }
        return (Pt(lm, tb) - Pt(lm, ta)) * 0.5f;
    };
    auto accAt = [&](int lm, int tt) -> V3 {
        int ta, tb;
        if (tt == 0)           { ta = 0;      tb = 2;     }
        else if (tt == T - 1)  { ta = T - 3;  tb = T - 1; }
        else                   { ta = tt - 1; tb = tt + 1; }
        return (velAt(lm, tb) - velAt(lm, ta)) * 0.5f;
    };

    float fg = fmask[idx];
    float bg = bmask[idx];

    float F[NF];

    // ---------------- Block A: tips + curls + cross + d_ti (f 0..23) -------
    #pragma unroll
    for (int h = 0; h < 2; ++h) {
        int base = h * 21;
        V3 t_tip = P(base + 4),  i_tip = P(base + 8),  m_tip = P(base + 12);
        V3 r_tip = P(base + 16), p_tip = P(base + 20);
        int oa = h * 12;
        F[oa + 0] = dist3(t_tip, i_tip);
        F[oa + 1] = dist3(i_tip, m_tip);
        F[oa + 2] = dist3(m_tip, r_tip);
        F[oa + 3] = dist3(r_tip, p_tip);
        F[oa + 4] = dist3(t_tip, p_tip);
        V3 tm = P(base + 2),  tip_j = P(base + 3);
        F[oa + 5] = dist3(tm, t_tip) / (dist3(tm, tip_j) + 1e-4f);
        V3 im = P(base + 5),  ipj = P(base + 6);
        F[oa + 6] = dist3(im, i_tip) / (dist3(im, ipj) + 1e-4f);
        V3 mm = P(base + 9),  mpj = P(base + 10);
        F[oa + 7] = dist3(mm, m_tip) / (dist3(mm, mpj) + 1e-4f);
        V3 rm = P(base + 13), rpj = P(base + 14);
        F[oa + 8] = dist3(rm, r_tip) / (dist3(rm, rpj) + 1e-4f);
        V3 pm = P(base + 17), ppj = P(base + 18);
        F[oa + 9] = dist3(pm, p_tip) / (dist3(pm, ppj) + 1e-4f);
        F[oa + 10] = i_tip.x - m_tip.x;
        F[oa + 11] = dist3(t_tip, im);
    }

    // ---------------- Block B: face distances * fg (f 24..33) --------------
    V3 p0 = P(0), p21 = P(21);
    V3 nose = P(42), chin = P(43), fore = P(44);
    V3 itip0 = P(8), itip1 = P(29);
    F[24] = dist3(p0, nose) * fg;
    F[25] = dist3(p0, chin) * fg;
    F[26] = dist3(p0, fore) * fg;
    F[27] = dist3(p21, nose) * fg;
    F[28] = dist3(p21, chin) * fg;
    F[29] = dist3(p21, fore) * fg;
    F[30] = dist3(itip0, nose) * fg;
    F[31] = dist3(itip0, fore) * fg;
    F[32] = dist3(itip1, nose) * fg;
    F[33] = dist3(itip1, fore) * fg;

    // ---------------- Block C: joint angles (f 34..63) ---------------------
    {
        constexpr int TRI[15][3] = {
            {0, 1, 2},   {1, 2, 3},   {2, 3, 4},
            {0, 5, 6},   {5, 6, 7},   {6, 7, 8},
            {0, 9, 10},  {9, 10, 11}, {10, 11, 12},
            {0, 13, 14}, {13, 14, 15},{14, 15, 16},
            {0, 17, 18}, {17, 18, 19},{18, 19, 20}};
        #pragma unroll
        for (int h = 0; h < 2; ++h) {
            int base = h * 21;
            #pragma unroll
            for (int i = 0; i < 15; ++i) {
                V3 pj = P(base + TRI[i][1]);
                V3 v1 = P(base + TRI[i][0]) - pj;
                V3 v2 = P(base + TRI[i][2]) - pj;
                F[34 + h * 15 + i] = acosc(dot3(v1, v2) / (norm3(v1) * norm3(v2) + 1e-6f));
            }
        }
    }

    // ---------------- Block D: palm normals (f 64..69) ---------------------
    V3 nrm[2];
    #pragma unroll
    for (int h = 0; h < 2; ++h) {
        int base = h * 21;
        V3 w = (h == 0) ? p0 : p21;
        V3 n = cross3(P(base + 5) - w, P(base + 17) - w);
        float inv = 1.0f / (norm3(n) + 1e-6f);
        n = n * inv;
        nrm[h] = n;
        F[64 + 3 * h + 0] = n.x;
        F[64 + 3 * h + 1] = n.y;
        F[64 + 3 * h + 2] = n.z;
    }

    // ---------------- Block E: spread angles (f 70..75) --------------------
    #pragma unroll
    for (int h = 0; h < 2; ++h) {
        int base = h * 21;
        V3 w = (h == 0) ? p0 : p21;
        V3 v5  = P(base + 5)  - w;
        V3 v9  = P(base + 9)  - w;
        V3 v13 = P(base + 13) - w;
        V3 v17 = P(base + 17) - w;
        F[70 + 3 * h + 0] = acosc(dot3(v5,  v9)  / (norm3(v5)  * norm3(v9)  + 1e-6f));
        F[70 + 3 * h + 1] = acosc(dot3(v9,  v13) / (norm3(v9)  * norm3(v13) + 1e-6f));
        F[70 + 3 * h + 2] = acosc(dot3(v13, v17) / (norm3(v13) * norm3(v17) + 1e-6f));
    }

    // ---------------- Block F: n . up, n . fwd (f 76..79) ------------------
    #pragma unroll
    for (int h = 0; h < 2; ++h) {
        F[76 + 2 * h + 0] = nrm[h].y;
        F[76 + 2 * h + 1] = nrm[h].z;
    }

    // ---------------- Block G: velocity direction (f 80..85) ---------------
    V3 velW[2];
    #pragma unroll
    for (int h = 0; h < 2; ++h) {
        V3 v = velAt(h * 21, t);
        velW[h] = v;
        float inv = 1.0f / fmaxf(norm3(v), 1e-6f);   // jnp.maximum semantics
        F[80 + 3 * h + 0] = v.x * inv;
        F[80 + 3 * h + 1] = v.y * inv;
        F[80 + 3 * h + 2] = v.z * inv;
    }

    // ---------------- Block H: velocity-turn angle (f 86..87) --------------
    #pragma unroll
    for (int h = 0; h < 2; ++h) {
        float val = 0.0f;
        if (t < T - 1) {
            V3 v0 = velW[h];
            V3 v1 = velAt(h * 21, t + 1);
            V3 a = v0 * (1.0f / (norm3(v0) + 1e-6f));
            V3 c = v1 * (1.0f / (norm3(v1) + 1e-6f));
            val = acosc(dot3(a, c));
        }
        F[86 + h] = val;
    }

    // ---------------- Block I/J: inter-hand (f 88..90) ---------------------
    F[88] = dist3(p0, p21);
    {
        V3 rel = p21 - p0;
        float inv = 1.0f / (norm3(rel) + 1e-6f);
        F[89] = rel.x * inv;
        F[90] = rel.y * inv;
    }

    // ---------------- Block K: d/dt dist-to-nose (f 91..92) ----------------
    #pragma unroll
    for (int h = 0; h < 2; ++h) {
        int lm = h * 21;
        int ta, tb;
        if (t == 0)          { ta = 0;      tb = 2;     }
        else if (t == T - 1) { ta = T - 3;  tb = T - 1; }
        else                 { ta = t - 1;  tb = t + 1; }
        float da = norm3(Pt(lm, ta) - Pt(42, ta));
        float db = norm3(Pt(lm, tb) - Pt(42, tb));
        F[91 + h] = (db - da) * 0.5f;
    }

    // ---------------- Block L: tip x-diffs (f 93..96) ----------------------
    #pragma unroll
    for (int h = 0; h < 2; ++h) {
        int base = h * 21;
        float ix = P(base + 8).x, mx = P(base + 12).x, rx = P(base + 16).x;
        F[93 + 2 * h + 0] = ix - mx;
        F[93 + 2 * h + 1] = mx - rx;
    }

    // ---------------- Block M: hand-velocity alignment (f 97) --------------
    {
        V3 ldv = velW[0] * (1.0f / (norm3(velW[0]) + 1e-6f));
        V3 rdv = velW[1] * (1.0f / (norm3(velW[1]) + 1e-6f));
        F[97] = dot3(ldv, rdv);
    }

    // ---------------- Block N: speed (f 98..99) ----------------------------
    F[98] = norm3(velW[0]);
    F[99] = norm3(velW[1]);

    // ---------------- Block O: accel magnitude (f 100..101) ----------------
    F[100] = norm3(accAt(0, t));
    F[101] = norm3(accAt(21, t));

    // ---------------- Block P: proximity sigmoid (f 102) -------------------
    {
        float hd = norm3(p0 - p21);
        F[102] = 1.0f / (1.0f + expf(-5.0f * (0.05f - hd)));
    }

    // ---------------- Block Q: body features * bg (f 103..113) -------------
    {
        V3 lsh = P(45), rsh = P(46);
        V3 shmid = (lsh + rsh) * 0.5f;
        float shw = dist3(lsh, rsh);
        float invw = 1.0f / (shw + 1e-6f);
        F[103] = (p0.y - shmid.y) * invw * bg;
        F[104] = (p0.x - shmid.x) * invw * bg;
        F[105] = dist3(p0, lsh) * bg;
        F[106] = dist3(p0, P(47)) * bg;
        F[107] = (p21.y - shmid.y) * invw * bg;
        F[108] = (p21.x - shmid.x) * invw * bg;
        F[109] = dist3(p21, rsh) * bg;
        F[110] = dist3(p21, P(48)) * bg;
        F[111] = shw * bg;
        V3 mouth = (P(49) + P(50)) * 0.5f;
        F[112] = dist3(p0, mouth) * bg;
        F[113] = dist3(p21, mouth) * bg;
    }

    // ---------------- burst store: temporally-compact dirty region ---------
    float* o = out + (size_t)idx * NF;
    #pragma unroll
    for (int f = 0; f < NF; ++f) o[f] = F[f];
}

// ---------------------------------------------------------------------------
// Fallback: round-1 direct kernel (used only if ws_size is insufficient)
// ---------------------------------------------------------------------------
__constant__ int c_TRI[15][3] = {
    {0, 1, 2},   {1, 2, 3},   {2, 3, 4},
    {0, 5, 6},   {5, 6, 7},   {6, 7, 8},
    {0, 9, 10},  {9, 10, 11}, {10, 11, 12},
    {0, 13, 14}, {13, 14, 15},{14, 15, 16},
    {0, 17, 18}, {17, 18, 19},{18, 19, 20}};

__global__ __launch_bounds__(256) void geo_direct(
    const float* __restrict__ xyz,
    const float* __restrict__ fmask,
    const float* __restrict__ bmask,
    float* __restrict__ out,
    int BT, int T)
{
    int idx = blockIdx.x * blockDim.x + threadIdx.x;
    if (idx >= BT) return;
    int b = idx / T;
    int t = idx - b * T;
    int bT0 = b * T;

    auto ldp = [&](int tt, int lm) -> V3 {
        const float* p = xyz + ((size_t)(bT0 + tt) * NLM + (size_t)lm) * 3;
        return V3{p[0], p[1], p[2]};
    };
    auto P = [&](int lm) -> V3 { return ldp(t, lm); };
    auto velAt = [&](int lm, int tt) -> V3 {
        int ta, tb;
        if (tt == 0)           { ta = 0;      tb = 2;     }
        else if (tt == T - 1)  { ta = T - 3;  tb = T - 1; }
        else                   { ta = tt - 1; tb = tt + 1; }
        return (ldp(tb, lm) - ldp(ta, lm)) * 0.5f;
    };
    auto accAt = [&](int lm, int tt) -> V3 {
        int ta, tb;
        if (tt == 0)           { ta = 0;      tb = 2;     }
        else if (tt == T - 1)  { ta = T - 3;  tb = T - 1; }
        else                   { ta = tt - 1; tb = tt + 1; }
        return (velAt(lm, tb) - velAt(lm, ta)) * 0.5f;
    };

    float fg = fmask[idx];
    float bg = bmask[idx];
    float* o = out + (size_t)idx * NF;

    for (int h = 0; h < 2; ++h) {
        int base = h * 21;
        V3 t_tip = P(base + 4),  i_tip = P(base + 8),  m_tip = P(base + 12);
        V3 r_tip = P(base + 16), p_tip = P(base + 20);
        float* oa = o + h * 12;
        oa[0] = dist3(t_tip, i_tip);
        oa[1] = dist3(i_tip, m_tip);
        oa[2] = dist3(m_tip, r_tip);
        oa[3] = dist3(r_tip, p_tip);
        oa[4] = dist3(t_tip, p_tip);
        V3 tm = P(base + 2),  tip_j = P(base + 3);
        oa[5] = dist3(tm, t_tip) / (dist3(tm, tip_j) + 1e-4f);
        V3 im = P(base + 5),  ipj = P(base + 6);
        oa[6] = dist3(im, i_tip) / (dist3(im, ipj) + 1e-4f);
        V3 mm = P(base + 9),  mpj = P(base + 10);
        oa[7] = dist3(mm, m_tip) / (dist3(mm, mpj) + 1e-4f);
        V3 rm = P(base + 13), rpj = P(base + 14);
        oa[8] = dist3(rm, r_tip) / (dist3(rm, rpj) + 1e-4f);
        V3 pm = P(base + 17), ppj = P(base + 18);
        oa[9] = dist3(pm, p_tip) / (dist3(pm, ppj) + 1e-4f);
        oa[10] = i_tip.x - m_tip.x;
        oa[11] = dist3(t_tip, im);
    }

    V3 p0 = P(0), p21 = P(21);
    V3 nose = P(42), chin = P(43), fore = P(44);
    V3 itip0 = P(8), itip1 = P(29);
    o[24] = dist3(p0, nose) * fg;
    o[25] = dist3(p0, chin) * fg;
    o[26] = dist3(p0, fore) * fg;
    o[27] = dist3(p21, nose) * fg;
    o[28] = dist3(p21, chin) * fg;
    o[29] = dist3(p21, fore) * fg;
    o[30] = dist3(itip0, nose) * fg;
    o[31] = dist3(itip0, fore) * fg;
    o[32] = dist3(itip1, nose) * fg;
    o[33] = dist3(itip1, fore) * fg;

    for (int h = 0; h < 2; ++h) {
        int base = h * 21;
        for (int i = 0; i < 15; ++i) {
            V3 pj = P(base + c_TRI[i][1]);
            V3 v1 = P(base + c_TRI[i][0]) - pj;
            V3 v2 = P(base + c_TRI[i][2]) - pj;
            o[34 + h * 15 + i] = acosc(dot3(v1, v2) / (norm3(v1) * norm3(v2) + 1e-6f));
        }
    }

    V3 nrm[2];
    for (int h = 0; h < 2; ++h) {
        int base = h * 21;
        V3 w = (h == 0) ? p0 : p21;
        V3 n = cross3(P(base + 5) - w, P(base + 17) - w);
        float inv = 1.0f / (norm3(n) + 1e-6f);
        n = n * inv;
        nrm[h] = n;
        o[64 + 3 * h + 0] = n.x;
        o[64 + 3 * h + 1] = n.y;
        o[64 + 3 * h + 2] = n.z;
    }

    for (int h = 0; h < 2; ++h) {
        int base = h * 21;
        V3 w = (h == 0) ? p0 : p21;
        V3 v5  = P(base + 5)  - w;
        V3 v9  = P(base + 9)  - w;
        V3 v13 = P(base + 13) - w;
        V3 v17 = P(base + 17) - w;
        o[70 + 3 * h + 0] = acosc(dot3(v5,  v9)  / (norm3(v5)  * norm3(v9)  + 1e-6f));
        o[70 + 3 * h + 1] = acosc(dot3(v9,  v13) / (norm3(v9)  * norm3(v13) + 1e-6f));
        o[70 + 3 * h + 2] = acosc(dot3(v13, v17) / (norm3(v13) * norm3(v17) + 1e-6f));
    }

    for (int h = 0; h < 2; ++h) {
        o[76 + 2 * h + 0] = nrm[h].y;
        o[76 + 2 * h + 1] = nrm[h].z;
    }

    V3 velW[2];
    for (int h = 0; h < 2; ++h) {
        V3 v = velAt(h * 21, t);
        velW[h] = v;
        float inv = 1.0f / fmaxf(norm3(v), 1e-6f);
        o[80 + 3 * h + 0] = v.x * inv;
        o[80 + 3 * h + 1] = v.y * inv;
        o[80 + 3 * h + 2] = v.z * inv;
    }

    for (int h = 0; h < 2; ++h) {
        float val = 0.0f;
        if (t < T - 1) {
            V3 v0 = velW[h];
            V3 v1 = velAt(h * 21, t + 1);
            V3 a = v0 * (1.0f / (norm3(v0) + 1e-6f));
            V3 c = v1 * (1.0f / (norm3(v1) + 1e-6f));
            val = acosc(dot3(a, c));
        }
        o[86 + h] = val;
    }

    o[88] = dist3(p0, p21);
    {
        V3 rel = p21 - p0;
        float inv = 1.0f / (norm3(rel) + 1e-6f);
        o[89] = rel.x * inv;
        o[90] = rel.y * inv;
    }

    for (int h = 0; h < 2; ++h) {
        int lm = h * 21;
        int ta, tb;
        if (t == 0)          { ta = 0;      tb = 2;     }
        else if (t == T - 1) { ta = T - 3;  tb = T - 1; }
        else                 { ta = t - 1;  tb = t + 1; }
        float da = norm3(ldp(ta, lm) - ldp(ta, 42));
        float db = norm3(ldp(tb, lm) - ldp(tb, 42));
        o[91 + h] = (db - da) * 0.5f;
    }

    for (int h = 0; h < 2; ++h) {
        int base = h * 21;
        float ix = P(base + 8).x, mx = P(base + 12).x, rx = P(base + 16).x;
        o[93 + 2 * h + 0] = ix - mx;
        o[93 + 2 * h + 1] = mx - rx;
    }

    {
        V3 ldv = velW[0] * (1.0f / (norm3(velW[0]) + 1e-6f));
        V3 rdv = velW[1] * (1.0f / (norm3(velW[1]) + 1e-6f));
        o[97] = dot3(ldv, rdv);
    }

    o[98] = norm3(velW[0]);
    o[99] = norm3(velW[1]);
    o[100] = norm3(accAt(0, t));
    o[101] = norm3(accAt(21, t));

    {
        float hd = norm3(p0 - p21);
        o[102] = 1.0f / (1.0f + expf(-5.0f * (0.05f - hd)));
    }

    {
        V3 lsh = P(45), rsh = P(46);
        V3 shmid = (lsh + rsh) * 0.5f;
        float shw = dist3(lsh, rsh);
        float invw = 1.0f / (shw + 1e-6f);
        o[103] = (p0.y - shmid.y) * invw * bg;
        o[104] = (p0.x - shmid.x) * invw * bg;
        o[105] = dist3(p0, lsh) * bg;
        o[106] = dist3(p0, P(47)) * bg;
        o[107] = (p21.y - shmid.y) * invw * bg;
        o[108] = (p21.x - shmid.x) * invw * bg;
        o[109] = dist3(p21, rsh) * bg;
        o[110] = dist3(p21, P(48)) * bg;
        o[111] = shw * bg;
        V3 mouth = (P(49) + P(50)) * 0.5f;
        o[112] = dist3(p0, mouth) * bg;
        o[113] = dist3(p21, mouth) * bg;
    }
}

extern "C" void kernel_launch(void* const* d_in, const int* in_sizes, int n_in,
                              void* d_out, int out_size, void* d_ws, size_t ws_size,
                              hipStream_t stream) {
    const float* xyz   = (const float*)d_in[0];
    const float* fmask = (const float*)d_in[1];
    const float* bmask = (const float*)d_in[2];
    float* out = (float*)d_out;

    const int BT = in_sizes[1];   // B*T = 131072 (face_mask element count)
    const int T  = 512;           // per reference setup_inputs

    size_t needed = (size_t)NC * (size_t)BT * sizeof(float);
    if (ws_size >= needed) {
        float* xt = (float*)d_ws;
        dim3 tb(32, 8);
        dim3 tg((BT + TDIM - 1) / TDIM, (NC + TDIM - 1) / TDIM);
        transpose_kernel<<<tg, tb, 0, stream>>>(xyz, xt, BT);
        const int threads = 256;
        geo_fast<<<(BT + threads - 1) / threads, threads, 0, stream>>>(
            xt, fmask, bmask, out, BT, T);
    } else {
        const int threads = 256;
        geo_direct<<<(BT + threads - 1) / threads, threads, 0, stream>>>(
            xyz, fmask, bmask, out, BT, T);
    }
}